// Round 14
// baseline (69.726 us; speedup 1.0000x reference)
//
#include <hip/hip_runtime.h>
#include <hip/hip_bf16.h>

typedef __attribute__((ext_vector_type(8))) short short8;
typedef __attribute__((ext_vector_type(4))) float f32x4;
typedef __attribute__((ext_vector_type(2))) float f32x2;
typedef __attribute__((ext_vector_type(4))) unsigned int u32x4;

#define NROWS   262144
#define ODIM    64
#define NBLOCKS 512
#define TPB     512           // 8 waves = 2 row-halves x 4 k-quarters
#define UPB     8             // units per block: 512*8 = 4096 = NROWS/64
#define INV2PI  0.15915494309189535f

__device__ __forceinline__ float cos2pi(float f){ float r; asm("v_cos_f32 %0, %1" : "=v"(r) : "v"(f)); return r; }
__device__ __forceinline__ float sin2pi(float f){ float r; asm("v_sin_f32 %0, %1" : "=v"(r) : "v"(f)); return r; }
__device__ __forceinline__ f32x2 pk_mul(f32x2 a, f32x2 b){
    f32x2 d; asm("v_pk_mul_f32 %0, %1, %2" : "=v"(d) : "v"(a), "v"(b)); return d; }
__device__ __forceinline__ f32x2 pk_fma(f32x2 a, f32x2 b, f32x2 c){
    f32x2 d; asm("v_pk_fma_f32 %0, %1, %2, %3" : "=v"(d) : "v"(a), "v"(b), "v"(c)); return d; }
__device__ __forceinline__ f32x2 pk_fms(f32x2 a, f32x2 b, f32x2 c){   // a*b - c
    f32x2 d; asm("v_pk_fma_f32 %0, %1, %2, %3 neg_lo:[0,0,1] neg_hi:[0,0,1]"
                 : "=v"(d) : "v"(a), "v"(b), "v"(c)); return d; }
__device__ __forceinline__ unsigned pkbf(float lo, float hi){
    unsigned r; asm("v_cvt_pk_bf16_f32 %0, %1, %2" : "=v"(r) : "v"(lo), "v"(hi)); return r; }
__device__ __forceinline__ short8 as_s8(u32x4 v){ union{u32x4 u; short8 s;} x; x.u = v; return x.s; }
__device__ __forceinline__ short bf16_of(float f){
    union { __hip_bfloat16 h; short s; } u; u.h = __float2bfloat16(f); return u.s; }

// out[b,o] = sum_k F[b,k] W[o,k]; k = br*384 + i*128 + g; harmonic = g+1
// K-split: paired-kk p in [0,12) (cos step p, sin step p+12 share harmonics).
// wave (rh, kw): rows [rh*32, rh*32+32) of each unit, paired-kk {3kw, 3kw+1, 3kw+2}.
// B-frags live in registers for the whole kernel; LDS only for the partial-sum reduction.
extern "C" __global__ void __launch_bounds__(TPB, 2)
fourier_ksplit(const float* __restrict__ x,
               const float* __restrict__ coeffs,
               const float* __restrict__ bias,
               float* __restrict__ out)
{
    __shared__ float Plds[8][32*64];   // 64 KB: [slot = rh*4+kw][reg*64 + lane]

    const int tid  = threadIdx.x;
    const int lane = tid & 63;
    const int wid  = tid >> 6;
    const int rh   = wid >> 2;        // row-half of the unit
    const int kw   = wid & 3;         // k-quarter
    const int mrow = lane & 15;       // A/B-frag row/col within 16-tile
    const int kgrp = lane >> 4;       // k sub-band (4-wide)

    // ---- B gather: fp32 coeffs -> 24 bf16 frags in registers (once per block) ----
    // frag element s[h*4+j] <-> k = ks*32 + h*16 + kgrp*4 + j  (verbatim R12 mapping)
    short8 Breg[3][2][4];             // [c][branch][nt] — all static indices
    #pragma unroll
    for (int c = 0; c < 3; ++c) {
        #pragma unroll
        for (int br = 0; br < 2; ++br) {
            #pragma unroll
            for (int nt = 0; nt < 4; ++nt) {
                const int ks = 3*kw + c;            // cos-step id 0..11 (same harmonics for sin)
                const int o  = nt*16 + mrow;
                union { short8 v; short s[8]; } fr;
                #pragma unroll
                for (int h = 0; h < 2; ++h) {
                    const int rem = ks*32 + h*16;   // [0,384)
                    const int ii  = rem >> 7;
                    const int g0  = (rem & 127) + kgrp*4;
                    const float* wp = coeffs + (((br*ODIM + o)*3 + ii) << 7) + g0;
                    #pragma unroll
                    for (int j = 0; j < 4; ++j) fr.s[h*4 + j] = bf16_of(wp[j]);
                }
                Breg[c][br][nt] = fr.v;
            }
        }
    }

    const float hs = (float)(4*kgrp + 1);   // lane's base harmonic within a 16-block
    const float bv = bias[lane];            // reduction col of lane l is exactly l

    #pragma unroll 1
    for (int uu = 0; uu < UPB; ++uu) {
        const int unit  = blockIdx.x * UPB + uu;
        const int rbase = unit*64 + rh*32;
        const int rowA  = rbase + mrow;          // row-tile 0 (chain .x)
        const int rowB  = rbase + 16 + mrow;     // row-tile 1 (chain .y)

        f32x2 xr[3];
        #pragma unroll
        for (int i = 0; i < 3; ++i)
            xr[i] = (f32x2){ x[rowA*3 + i] * INV2PI, x[rowB*3 + i] * INV2PI };

        f32x4 acc[2][4];
        #pragma unroll
        for (int rt = 0; rt < 2; ++rt)
            #pragma unroll
            for (int nt = 0; nt < 4; ++nt)
                acc[rt][nt] = (f32x4){0.f, 0.f, 0.f, 0.f};

        f32x2 cvp, svp, c16p, s16p, stc, sts;

        #pragma unroll
        for (int c = 0; c < 3; ++c) {
            const int p = 3*kw + c;              // paired-kk 0..11 (runtime, wave-uniform)
            if (c == 0 || (p & 3) == 0) {        // (re-)anchor at wave start / i-boundary
                const int ii = p >> 2;
                const float moff = (float)(32 * (p & 3));   // harmonic offset into i-block
                const f32x2 a = xr[ii];
                cvp = (f32x2){ cos2pi(a.x), cos2pi(a.y) };   // rotate by 1*x
                svp = (f32x2){ sin2pi(a.x), sin2pi(a.y) };
                f32x2 t = (f32x2){ 16.f*a.x, 16.f*a.y };
                t.x -= floorf(t.x); t.y -= floorf(t.y);
                c16p = (f32x2){ cos2pi(t.x), cos2pi(t.y) };  // rotate by 16*x
                s16p = (f32x2){ sin2pi(t.x), sin2pi(t.y) };
                const float hm = hs + moff;
                f32x2 u = (f32x2){ hm*a.x, hm*a.y };
                u.x -= floorf(u.x); u.y -= floorf(u.y);
                stc = (f32x2){ cos2pi(u.x), cos2pi(u.y) };   // state: harmonic hm
                sts = (f32x2){ sin2pi(u.x), sin2pi(u.y) };
            }

            // FEAT (verbatim R12, proven): packed rotations + cvt_pk packing
            u32x4 FCA, FCB, FSA, FSB;
            {
                // h = 0
                f32x2 c0 = stc, s0 = sts;
                f32x2 c1 = pk_fms(c0, cvp, pk_mul(s0, svp));
                f32x2 s1 = pk_fma(s0, cvp, pk_mul(c0, svp));
                FCA.x = pkbf(c0.x, c1.x);  FCB.x = pkbf(c0.y, c1.y);
                FSA.x = pkbf(s0.x, s1.x);  FSB.x = pkbf(s0.y, s1.y);
                f32x2 c2 = pk_fms(c1, cvp, pk_mul(s1, svp));
                f32x2 s2 = pk_fma(s1, cvp, pk_mul(c1, svp));
                f32x2 c3 = pk_fms(c2, cvp, pk_mul(s2, svp));
                f32x2 s3 = pk_fma(s2, cvp, pk_mul(c2, svp));
                FCA.y = pkbf(c2.x, c3.x);  FCB.y = pkbf(c2.y, c3.y);
                FSA.y = pkbf(s2.x, s3.x);  FSB.y = pkbf(s2.y, s3.y);
                f32x2 nc = pk_fms(stc, c16p, pk_mul(sts, s16p));
                f32x2 ns = pk_fma(sts, c16p, pk_mul(stc, s16p));
                stc = nc; sts = ns;
                // h = 1
                c0 = stc; s0 = sts;
                c1 = pk_fms(c0, cvp, pk_mul(s0, svp));
                s1 = pk_fma(s0, cvp, pk_mul(c0, svp));
                FCA.z = pkbf(c0.x, c1.x);  FCB.z = pkbf(c0.y, c1.y);
                FSA.z = pkbf(s0.x, s1.x);  FSB.z = pkbf(s0.y, s1.y);
                c2 = pk_fms(c1, cvp, pk_mul(s1, svp));
                s2 = pk_fma(s1, cvp, pk_mul(c1, svp));
                c3 = pk_fms(c2, cvp, pk_mul(s2, svp));
                s3 = pk_fma(s2, cvp, pk_mul(c2, svp));
                FCA.w = pkbf(c2.x, c3.x);  FCB.w = pkbf(c2.y, c3.y);
                FSA.w = pkbf(s2.x, s3.x);  FSB.w = pkbf(s2.y, s3.y);
                nc = pk_fms(stc, c16p, pk_mul(sts, s16p));
                ns = pk_fma(sts, c16p, pk_mul(stc, s16p));
                stc = nc; sts = ns;
            }

            const short8 fAc = as_s8(FCA);
            const short8 fBc = as_s8(FCB);
            const short8 fAs = as_s8(FSA);
            const short8 fBs = as_s8(FSB);

            // 16 MFMAs, all operands in registers; acc reuse distance = 8
            #pragma unroll
            for (int nt = 0; nt < 4; ++nt)
                acc[0][nt] = __builtin_amdgcn_mfma_f32_16x16x32_bf16(fAc, Breg[c][0][nt], acc[0][nt], 0, 0, 0);
            #pragma unroll
            for (int nt = 0; nt < 4; ++nt)
                acc[1][nt] = __builtin_amdgcn_mfma_f32_16x16x32_bf16(fBc, Breg[c][0][nt], acc[1][nt], 0, 0, 0);
            #pragma unroll
            for (int nt = 0; nt < 4; ++nt)
                acc[0][nt] = __builtin_amdgcn_mfma_f32_16x16x32_bf16(fAs, Breg[c][1][nt], acc[0][nt], 0, 0, 0);
            #pragma unroll
            for (int nt = 0; nt < 4; ++nt)
                acc[1][nt] = __builtin_amdgcn_mfma_f32_16x16x32_bf16(fBs, Breg[c][1][nt], acc[1][nt], 0, 0, 0);
        }

        // barrier A: previous unit's reduction reads are done before we overwrite slots
        __syncthreads();

        // dump partials (raw acc order; layout decoded at reduce)
        {
            const int slot = rh*4 + kw;
            #pragma unroll
            for (int rt = 0; rt < 2; ++rt)
                #pragma unroll
                for (int nt = 0; nt < 4; ++nt)
                    #pragma unroll
                    for (int q = 0; q < 4; ++q)
                        Plds[slot][((rt*4 + nt)*4 + q)*64 + lane] = acc[rt][nt][q];
        }

        // barrier B: partials visible
        __syncthreads();

        // reduce: wave `wid` owns unit-rows [wid*8, wid*8+8); lane l owns col l.
        // D layout: col = lane&15 (+16*nt), row-in-tile = 4*(lane>>4) + q  [m89-verified]
        #pragma unroll
        for (int rr = 0; rr < 8; ++rr) {
            const int r     = wid*8 + rr;                       // row within unit
            const int lane2 = (((r & 15) >> 2) << 4) | (lane & 15);
            const int reg   = (((r >> 4) & 1)*4 + (lane >> 4))*4 + (r & 3);
            const int sb    = (r >> 5)*4;                       // source row-half's slots
            const float s = Plds[sb+0][reg*64 + lane2] + Plds[sb+1][reg*64 + lane2]
                          + Plds[sb+2][reg*64 + lane2] + Plds[sb+3][reg*64 + lane2];
            out[(unit*64 + r)*ODIM + lane] = s + bv;
        }
        // reduction reads of this unit are fenced from next unit's writes by barrier A
    }
}

extern "C" void kernel_launch(void* const* d_in, const int* in_sizes, int n_in,
                              void* d_out, int out_size, void* d_ws, size_t ws_size,
                              hipStream_t stream) {
    const float* x      = (const float*)d_in[0];
    const float* coeffs = (const float*)d_in[1];
    const float* bias   = (const float*)d_in[2];
    float* out = (float*)d_out;
    (void)in_sizes; (void)n_in; (void)out_size; (void)d_ws; (void)ws_size;
    hipLaunchKernelGGL(fourier_ksplit, dim3(NBLOCKS), dim3(TPB), 0, stream, x, coeffs, bias, out);
}

// Round 15
// 50.898 us; speedup vs baseline: 1.3699x; 1.3699x over previous
//
#include <hip/hip_runtime.h>
#include <hip/hip_bf16.h>

typedef __attribute__((ext_vector_type(8)))  short short8;
typedef __attribute__((ext_vector_type(16))) float f32x16;
typedef __attribute__((ext_vector_type(2)))  float f32x2;
typedef __attribute__((ext_vector_type(4)))  unsigned int u32x4;

#define NROWS   262144
#define ODIM    64
#define NBLOCKS 256
#define TPB     1024          // 16 waves; 98 KB LDS -> 1 block/CU -> 4 waves/SIMD
#define INV2PI  0.15915494309189535f

__device__ __forceinline__ float cos2pi(float f){ float r; asm("v_cos_f32 %0, %1" : "=v"(r) : "v"(f)); return r; }
__device__ __forceinline__ float sin2pi(float f){ float r; asm("v_sin_f32 %0, %1" : "=v"(r) : "v"(f)); return r; }
// D.lo = bf16(lo), D.hi = bf16(hi), RNE
__device__ __forceinline__ unsigned pkbf(float lo, float hi){
    unsigned r; asm("v_cvt_pk_bf16_f32 %0, %1, %2" : "=v"(r) : "v"(lo), "v"(hi)); return r; }
__device__ __forceinline__ short8 as_s8(u32x4 v){ union{u32x4 u; short8 s;} x; x.u = v; return x.s; }
__device__ __forceinline__ short bf16_of(float f){
    union { __hip_bfloat16 h; short s; } u; u.h = __float2bfloat16(f); return u.s; }

// out[b,o] = sum_k F[b,k] W[o,k]; k = br*384 + i*128 + g; harmonic = g+1.
// 32x32x16 MFMA. Pair p (0..23): cos k-block [p*16, p*16+16) + sin same block.
// A lane: row = l&31, k = (l>>5)*8 + j  (self-consistent with B pack)
// B lane: col = l&31, k = (l>>5)*8 + j
// D:      col = l&31, row = (q&3) + 8*(q>>2) + 4*(l>>5)   [m74/m101, R4-passed]
extern "C" __global__ void __launch_bounds__(TPB, 4)
fourier_mfma(const float* __restrict__ x,
             const float* __restrict__ coeffs,
             const float* __restrict__ bias,
             float* __restrict__ out)
{
    // [pair][br][ct][lane] -> short8 (one ds_read_b128 per b-frag)
    __shared__ short8 Wlds[24 * 2 * 2 * 64];   // 98304 B

    const int tid = threadIdx.x;

    // ---- one-time weight staging: fp32 global -> bf16 32x32-frags in LDS ----
    for (int fl = tid; fl < 24*2*2*64; fl += TPB) {
        const int ln = fl & 63;
        const int ct = (fl >> 6) & 1;
        const int br = (fl >> 7) & 1;
        const int p  = fl >> 8;
        const int o  = ct*32 + (ln & 31);
        const int kb = p*16 + (ln >> 5)*8;      // 8-run stays inside one i-block
        const int ii = kb >> 7;
        const int g0 = kb & 127;
        const float* wp = coeffs + (((br*ODIM + o)*3 + ii) << 7) + g0;
        union { short8 v; short s[8]; } fr;
        #pragma unroll
        for (int j = 0; j < 8; ++j) fr.s[j] = bf16_of(wp[j]);
        Wlds[fl] = fr.v;
    }
    __syncthreads();

    const int lane = tid & 63;
    const int wid  = tid >> 6;
    const int col  = lane & 31;      // A row-in-tile / B col / D col
    const int kbd  = lane >> 5;      // k sub-band (8-wide)
    const float hs = (float)(kbd*8 + 1);   // lane's anchor harmonic per i-block

    const int unit = blockIdx.x * 16 + wid;   // 4096 units = NROWS/64, exact
    const int base = unit * 64;
    const int rowA = base + col;              // row-tile 0 (chain .x)
    const int rowB = base + 32 + col;         // row-tile 1 (chain .y)

    f32x2 xr[3];
    #pragma unroll
    for (int i = 0; i < 3; ++i)
        xr[i] = (f32x2){ x[rowA*3 + i] * INV2PI, x[rowB*3 + i] * INV2PI };

    const float bias0 = bias[col];
    const float bias1 = bias[32 + col];

    f32x16 acc[2][2];   // [rt][ct]
    #pragma unroll
    for (int rt = 0; rt < 2; ++rt)
        #pragma unroll
        for (int ct = 0; ct < 2; ++ct)
            #pragma unroll
            for (int q = 0; q < 16; ++q) acc[rt][ct][q] = 0.f;

    f32x2 cvp, svp, c16p, s16p, stc, sts;

    #pragma unroll 1
    for (int p = 0; p < 24; ++p) {
        // cos b-frags for this pair (early; chain math below covers LDS latency)
        const short8 bc0 = Wlds[((p*2 + 0)*2 + 0)*64 + lane];
        const short8 bc1 = Wlds[((p*2 + 0)*2 + 1)*64 + lane];

        if ((p & 7) == 0) {                    // per-input-dim anchor (uniform branch)
            const int i = p >> 3;
            const f32x2 a = xr[i];
            cvp = (f32x2){ cos2pi(a.x), cos2pi(a.y) };   // rotate by 1*x
            svp = (f32x2){ sin2pi(a.x), sin2pi(a.y) };
            f32x2 t = (f32x2){ 16.f*a.x, 16.f*a.y };
            t.x -= floorf(t.x); t.y -= floorf(t.y);
            c16p = (f32x2){ cos2pi(t.x), cos2pi(t.y) };  // rotate by 16*x
            s16p = (f32x2){ sin2pi(t.x), sin2pi(t.y) };
            f32x2 u = (f32x2){ hs*a.x, hs*a.y };
            u.x -= floorf(u.x); u.y -= floorf(u.y);
            stc = (f32x2){ cos2pi(u.x), cos2pi(u.y) };   // state: harmonic kbd*8+1
            sts = (f32x2){ sin2pi(u.x), sin2pi(u.y) };
        }

        // 8-long rotation chain -> 4 A-frags (2 row-tiles x {cos,sin})
        u32x4 FC0, FC1, FS0, FS1;
        {
            f32x2 c = stc, s = sts;
            f32x2 cp = c, sp = s;
            // j = 0,1
            { const f32x2 cn = c*cvp - s*svp, sn = s*cvp + c*svp; c = cn; s = sn; }
            FC0.x = pkbf(cp.x, c.x);  FC1.x = pkbf(cp.y, c.y);
            FS0.x = pkbf(sp.x, s.x);  FS1.x = pkbf(sp.y, s.y);
            // j = 2,3
            { const f32x2 cn = c*cvp - s*svp, sn = s*cvp + c*svp; cp = cn; sp = sn; }
            { const f32x2 cn = cp*cvp - sp*svp, sn = sp*cvp + cp*svp; c = cn; s = sn; }
            FC0.y = pkbf(cp.x, c.x);  FC1.y = pkbf(cp.y, c.y);
            FS0.y = pkbf(sp.x, s.x);  FS1.y = pkbf(sp.y, s.y);
            // j = 4,5
            { const f32x2 cn = c*cvp - s*svp, sn = s*cvp + c*svp; cp = cn; sp = sn; }
            { const f32x2 cn = cp*cvp - sp*svp, sn = sp*cvp + cp*svp; c = cn; s = sn; }
            FC0.z = pkbf(cp.x, c.x);  FC1.z = pkbf(cp.y, c.y);
            FS0.z = pkbf(sp.x, s.x);  FS1.z = pkbf(sp.y, s.y);
            // j = 6,7
            { const f32x2 cn = c*cvp - s*svp, sn = s*cvp + c*svp; cp = cn; sp = sn; }
            { const f32x2 cn = cp*cvp - sp*svp, sn = sp*cvp + cp*svp; c = cn; s = sn; }
            FC0.w = pkbf(cp.x, c.x);  FC1.w = pkbf(cp.y, c.y);
            FS0.w = pkbf(sp.x, s.x);  FS1.w = pkbf(sp.y, s.y);
            // advance anchor by 16*x for the next pair
            const f32x2 nc = stc*c16p - sts*s16p;
            const f32x2 ns = sts*c16p + stc*s16p;
            stc = nc; sts = ns;
        }

        // cos MFMAs (4), then fetch sin b-frags (hidden under MFMA), then sin MFMAs (4)
        const short8 fc0 = as_s8(FC0), fc1 = as_s8(FC1);
        acc[0][0] = __builtin_amdgcn_mfma_f32_32x32x16_bf16(fc0, bc0, acc[0][0], 0, 0, 0);
        acc[0][1] = __builtin_amdgcn_mfma_f32_32x32x16_bf16(fc0, bc1, acc[0][1], 0, 0, 0);
        acc[1][0] = __builtin_amdgcn_mfma_f32_32x32x16_bf16(fc1, bc0, acc[1][0], 0, 0, 0);
        acc[1][1] = __builtin_amdgcn_mfma_f32_32x32x16_bf16(fc1, bc1, acc[1][1], 0, 0, 0);

        const short8 bs0 = Wlds[((p*2 + 1)*2 + 0)*64 + lane];
        const short8 bs1 = Wlds[((p*2 + 1)*2 + 1)*64 + lane];
        const short8 fs0 = as_s8(FS0), fs1 = as_s8(FS1);
        acc[0][0] = __builtin_amdgcn_mfma_f32_32x32x16_bf16(fs0, bs0, acc[0][0], 0, 0, 0);
        acc[0][1] = __builtin_amdgcn_mfma_f32_32x32x16_bf16(fs0, bs1, acc[0][1], 0, 0, 0);
        acc[1][0] = __builtin_amdgcn_mfma_f32_32x32x16_bf16(fs1, bs0, acc[1][0], 0, 0, 0);
        acc[1][1] = __builtin_amdgcn_mfma_f32_32x32x16_bf16(fs1, bs1, acc[1][1], 0, 0, 0);
    }

    // Epilogue (verbatim R4, numerically verified). D: col=l&31, row=(q&3)+8*(q>>2)+4*kbd
    #pragma unroll
    for (int rt = 0; rt < 2; ++rt) {
        #pragma unroll
        for (int ct = 0; ct < 2; ++ct) {
            const float bv = ct ? bias1 : bias0;
            #pragma unroll
            for (int q = 0; q < 16; ++q) {
                const int row = base + rt*32 + (q & 3) + 8*(q >> 2) + 4*kbd;
                out[row*ODIM + ct*32 + col] = acc[rt][ct][q] + bv;
            }
        }
    }
}

extern "C" void kernel_launch(void* const* d_in, const int* in_sizes, int n_in,
                              void* d_out, int out_size, void* d_ws, size_t ws_size,
                              hipStream_t stream) {
    const float* x      = (const float*)d_in[0];
    const float* coeffs = (const float*)d_in[1];
    const float* bias   = (const float*)d_in[2];
    float* out = (float*)d_out;
    (void)in_sizes; (void)n_in; (void)out_size; (void)d_ws; (void)ws_size;
    hipLaunchKernelGGL(fourier_mfma, dim3(NBLOCKS), dim3(TPB), 0, stream, x, coeffs, bias, out);
}

// Round 16
// 41.406 us; speedup vs baseline: 1.6840x; 1.2292x over previous
//
#include <hip/hip_runtime.h>
#include <hip/hip_bf16.h>

typedef __attribute__((ext_vector_type(8))) short short8;
typedef __attribute__((ext_vector_type(4))) float f32x4;
typedef __attribute__((ext_vector_type(2))) float f32x2;

#define NROWS   262144
#define ODIM    64
#define NBLOCKS 256
#define TPB     1024          // 16 waves; 98 KB LDS -> 1 block/CU -> 4 waves/SIMD
#define INV2PI  0.15915494309189535f

__device__ __forceinline__ float cos2pi(float f){ float r; asm("v_cos_f32 %0, %1" : "=v"(r) : "v"(f)); return r; }
__device__ __forceinline__ float sin2pi(float f){ float r; asm("v_sin_f32 %0, %1" : "=v"(r) : "v"(f)); return r; }

__device__ __forceinline__ short bf16_of(float f){
    union { __hip_bfloat16 h; short s; } u;
    u.h = __float2bfloat16(f);
    return u.s;
}

// out[b,o] = sum_k F[b,k] W[o,k]; k = br*384 + i*128 + g; harmonic = g+1
// cos k-step kk (0..11) pairs with sin k-step kk+12 (identical harmonics).
// R16 = R11 verbatim + amdgpu_waves_per_eu(4,4): LDS already caps occupancy at
// 4 waves/EU; the attribute tells the register allocator, unlocking the full
// 128-reg budget (kills the 2 MB/dispatch scratch spill seen as WRITE_SIZE 67584).
extern "C" __global__ void __launch_bounds__(TPB, 4)
__attribute__((amdgpu_waves_per_eu(4, 4)))
fourier_mfma(const float* __restrict__ x,
             const float* __restrict__ coeffs,
             const float* __restrict__ bias,
             float* __restrict__ out)
{
    // Fragment-ordered bf16 weights: [ks][nt][lane] -> 8 bf16 (one ds_read_b128)
    __shared__ short8 Wlds[24 * 4 * 64];   // 98304 B

    const int tid = threadIdx.x;

    // ---- one-time weight staging: fp32 global -> bf16 fragments in LDS ----
    for (int fl = tid; fl < 24*4*64; fl += TPB) {
        const int ks = fl >> 8;
        const int nt = (fl >> 6) & 3;
        const int ln = fl & 63;
        const int o  = nt*16 + (ln & 15);   // B-frag: col = lane & 15
        const int kg = ln >> 4;             // k sub-band = 4*(lane>>4)
        union { short8 v; short s[8]; } fr;
        #pragma unroll
        for (int h = 0; h < 2; ++h) {
            const int kb  = ks*32 + h*16;
            const int br  = (kb >= 384) ? 1 : 0;
            const int rem = kb - br*384;
            const int ii  = rem >> 7;
            const int g0  = (rem & 127) + kg*4;
            const float* wp = coeffs + (((br*ODIM + o)*3 + ii) << 7) + g0;
            #pragma unroll
            for (int j = 0; j < 4; ++j) fr.s[h*4 + j] = bf16_of(wp[j]);
        }
        Wlds[fl] = fr.v;
    }
    __syncthreads();

    const int lane = tid & 63;
    const int wid  = tid >> 6;
    const int mrow = lane & 15;     // A-frag row within 16-row tile
    const int kgrp = lane >> 4;     // k sub-band / D-row group
    const float hs = (float)(4*kgrp + 1);   // lane's starting harmonic per 16-block

    float bcol[4];
    #pragma unroll
    for (int nt = 0; nt < 4; ++nt) bcol[nt] = bias[nt*16 + mrow];

    const int unit = blockIdx.x * 16 + wid;   // 256*16 = 4096 units = NROWS/64
    const int base = unit * 64;

    // Two sequential 32-row passes; each pass handles a packed row-pair (rr=0,1).
    #pragma unroll 1
    for (int rg = 0; rg < 2; ++rg) {
        const int rowA = base + (rg*2 + 0)*16 + mrow;
        const int rowB = base + (rg*2 + 1)*16 + mrow;

        // Preload x (revolutions) for both rows, all 3 input dims.
        f32x2 xr[3];
        #pragma unroll
        for (int i = 0; i < 3; ++i)
            xr[i] = (f32x2){ x[rowA*3 + i] * INV2PI, x[rowB*3 + i] * INV2PI };

        f32x4 acc[2][4];
        #pragma unroll
        for (int rr = 0; rr < 2; ++rr)
            #pragma unroll
            for (int nt = 0; nt < 4; ++nt)
                acc[rr][nt] = (f32x4){0.f, 0.f, 0.f, 0.f};

        f32x2 cvp, svp, c16p, s16p, stc, sts;

        #pragma unroll 1
        for (int kk = 0; kk < 12; ++kk) {          // cos k-step; sin is kk+12
            // early-issue this step's 8 b-frags (latency hides under feature gen).
            short8 bfr[8];                          // [branch*4 + nt], static idx
            #pragma unroll
            for (int nt = 0; nt < 4; ++nt) {
                bfr[nt]     = Wlds[(kk*4 + nt)*64 + lane];
                bfr[4 + nt] = Wlds[((kk + 12)*4 + nt)*64 + lane];
            }

            if ((kk & 3) == 0) {                    // uniform branch, every 4th iter
                const int i = kk >> 2;
                const f32x2 a = xr[i];
                cvp = (f32x2){ cos2pi(a.x), cos2pi(a.y) };   // rotate by 1*x
                svp = (f32x2){ sin2pi(a.x), sin2pi(a.y) };
                f32x2 t = (f32x2){ 16.f*a.x, 16.f*a.y };
                t.x -= floorf(t.x); t.y -= floorf(t.y);
                c16p = (f32x2){ cos2pi(t.x), cos2pi(t.y) };  // rotate by 16*x
                s16p = (f32x2){ sin2pi(t.x), sin2pi(t.y) };
                f32x2 u = (f32x2){ hs*a.x, hs*a.y };
                u.x -= floorf(u.x); u.y -= floorf(u.y);
                stc = (f32x2){ cos2pi(u.x), cos2pi(u.y) };   // state: harmonic 4*kgrp+1
                sts = (f32x2){ sin2pi(u.x), sin2pi(u.y) };
            }

            union { short8 v; short s[8]; } fc[2], fs[2];
            #pragma unroll
            for (int h = 0; h < 2; ++h) {
                f32x2 c = stc, s = sts;
                fc[0].s[h*4] = bf16_of(c.x); fc[1].s[h*4] = bf16_of(c.y);
                fs[0].s[h*4] = bf16_of(s.x); fs[1].s[h*4] = bf16_of(s.y);
                #pragma unroll
                for (int j = 1; j < 4; ++j) {
                    const f32x2 cn = c*cvp - s*svp;   // dual rotation
                    const f32x2 sn = s*cvp + c*svp;
                    c = cn; s = sn;
                    fc[0].s[h*4+j] = bf16_of(c.x); fc[1].s[h*4+j] = bf16_of(c.y);
                    fs[0].s[h*4+j] = bf16_of(s.x); fs[1].s[h*4+j] = bf16_of(s.y);
                }
                const f32x2 nc = stc*c16p - sts*s16p; // advance state by 16*x
                const f32x2 ns = sts*c16p + stc*s16p;
                stc = nc; sts = ns;
            }

            #pragma unroll
            for (int nt = 0; nt < 4; ++nt) {
                #pragma unroll
                for (int rr = 0; rr < 2; ++rr) {
                    acc[rr][nt] = __builtin_amdgcn_mfma_f32_16x16x32_bf16(fc[rr].v, bfr[nt],     acc[rr][nt], 0, 0, 0);
                    acc[rr][nt] = __builtin_amdgcn_mfma_f32_16x16x32_bf16(fs[rr].v, bfr[4 + nt], acc[rr][nt], 0, 0, 0);
                }
            }
        }

        // Epilogue. D layout: col = lane&15, row = 4*(lane>>4) + reg  [m89-verified]
        #pragma unroll
        for (int rr = 0; rr < 2; ++rr) {
            const int row0 = base + (rg*2 + rr)*16 + kgrp*4;
            #pragma unroll
            for (int nt = 0; nt < 4; ++nt) {
                #pragma unroll
                for (int q = 0; q < 4; ++q) {
                    out[(row0 + q)*ODIM + nt*16 + mrow] = acc[rr][nt][q] + bcol[nt];
                }
            }
        }
    }
}

extern "C" void kernel_launch(void* const* d_in, const int* in_sizes, int n_in,
                              void* d_out, int out_size, void* d_ws, size_t ws_size,
                              hipStream_t stream) {
    const float* x      = (const float*)d_in[0];
    const float* coeffs = (const float*)d_in[1];
    const float* bias   = (const float*)d_in[2];
    float* out = (float*)d_out;
    (void)in_sizes; (void)n_in; (void)out_size; (void)d_ws; (void)ws_size;
    hipLaunchKernelGGL(fourier_mfma, dim3(NBLOCKS), dim3(TPB), 0, stream, x, coeffs, bias, out);
}

// Round 17
// 38.695 us; speedup vs baseline: 1.8020x; 1.0701x over previous
//
#include <hip/hip_runtime.h>
#include <hip/hip_fp16.h>

typedef __attribute__((ext_vector_type(8))) short short8;
typedef __attribute__((ext_vector_type(8))) _Float16 half8;
typedef __attribute__((ext_vector_type(4))) float f32x4;
typedef __attribute__((ext_vector_type(2))) float f32x2;
typedef __attribute__((ext_vector_type(4))) unsigned int u32x4;

#define NROWS   262144
#define ODIM    64
#define NBLOCKS 256
#define TPB     1024          // 16 waves; 98 KB LDS -> 1 block/CU -> 4 waves/SIMD
#define INV2PI  0.15915494309189535f

__device__ __forceinline__ float cos2pi(float f){ float r; asm("v_cos_f32 %0, %1" : "=v"(r) : "v"(f)); return r; }
__device__ __forceinline__ float sin2pi(float f){ float r; asm("v_sin_f32 %0, %1" : "=v"(r) : "v"(f)); return r; }

__device__ __forceinline__ short f16_of(float f){
    union { _Float16 h; short s; } u; u.h = (_Float16)f; return u.s; }
__device__ __forceinline__ unsigned h2b(__half2 h){
    union { __half2 h; unsigned u; } x; x.h = h; return x.u; }
__device__ __forceinline__ half8 u4h(u32x4 v){ union{u32x4 u; half8 h;} x; x.u = v; return x.h; }
__device__ __forceinline__ half8 s8h(short8 v){ union{short8 s; half8 h;} x; x.s = v; return x.h; }

// one packed rotation: (C,S) <- (C*rc - S*rs, S*rc + C*rs), 2 features/inst
#define ADV(C, S, RC, RS, RN) do {                       \
    const __half2 _cn = __hfma2(C, RC, __hmul2(S, RN));  \
    const __half2 _sn = __hfma2(S, RC, __hmul2(C, RS));  \
    C = _cn; S = _sn;                                    \
} while (0)

// out[b,o] = sum_k F[b,k] W[o,k]; k = br*384 + i*128 + g; harmonic = g+1
// cos k-step kk (0..11) pairs with sin k-step kk+12 (identical harmonics).
// Frag element s[h*4+j] <-> harmonic (kk&3)*32 + h*16 + kgrp*4 + j + 1 within i-block.
// Dword view: pairs at harmonic offsets {0,2,16,18} -> advances +2,+14,+2,+14 (chain
// carries across kk inside an i-block; re-anchored every 4 kk).
extern "C" __global__ void __launch_bounds__(TPB, 4)
__attribute__((amdgpu_waves_per_eu(4, 4)))
fourier_mfma(const float* __restrict__ x,
             const float* __restrict__ coeffs,
             const float* __restrict__ bias,
             float* __restrict__ out)
{
    // Fragment-ordered f16 weights: [ks][nt][lane] -> 8 f16 (one ds_read_b128)
    __shared__ short8 Wlds[24 * 4 * 64];   // 98304 B

    const int tid = threadIdx.x;

    // ---- one-time weight staging: fp32 global -> f16 fragments in LDS ----
    for (int fl = tid; fl < 24*4*64; fl += TPB) {
        const int ks = fl >> 8;
        const int nt = (fl >> 6) & 3;
        const int ln = fl & 63;
        const int o  = nt*16 + (ln & 15);   // B-frag: col = lane & 15
        const int kg = ln >> 4;             // k sub-band = 4*(lane>>4)
        union { short8 v; short s[8]; } fr;
        #pragma unroll
        for (int h = 0; h < 2; ++h) {
            const int kb  = ks*32 + h*16;
            const int br  = (kb >= 384) ? 1 : 0;
            const int rem = kb - br*384;
            const int ii  = rem >> 7;
            const int g0  = (rem & 127) + kg*4;
            const float* wp = coeffs + (((br*ODIM + o)*3 + ii) << 7) + g0;
            #pragma unroll
            for (int j = 0; j < 4; ++j) fr.s[h*4 + j] = f16_of(wp[j]);
        }
        Wlds[fl] = fr.v;
    }
    __syncthreads();

    const int lane = tid & 63;
    const int wid  = tid >> 6;
    const int mrow = lane & 15;     // A-frag row within 16-row tile
    const int kgrp = lane >> 4;     // k sub-band / D-row group
    const float hs = (float)(4*kgrp + 1);   // lane's anchor harmonic per i-block

    float bcol[4];
    #pragma unroll
    for (int nt = 0; nt < 4; ++nt) bcol[nt] = bias[nt*16 + mrow];

    const int unit = blockIdx.x * 16 + wid;   // 256*16 = 4096 units = NROWS/64
    const int base = unit * 64;

    // Two sequential 32-row passes; each pass handles a row-pair (rows r0, r1).
    #pragma unroll 1
    for (int rg = 0; rg < 2; ++rg) {
        const int rowA = base + (rg*2 + 0)*16 + mrow;
        const int rowB = base + (rg*2 + 1)*16 + mrow;

        f32x2 xr[3];
        #pragma unroll
        for (int i = 0; i < 3; ++i)
            xr[i] = (f32x2){ x[rowA*3 + i] * INV2PI, x[rowB*3 + i] * INV2PI };

        f32x4 acc[2][4];
        #pragma unroll
        for (int rr = 0; rr < 2; ++rr)
            #pragma unroll
            for (int nt = 0; nt < 4; ++nt)
                acc[rr][nt] = (f32x4){0.f, 0.f, 0.f, 0.f};

        // chain state + rotation constants (per row)
        __half2 C0, S0, C1, S1;
        __half2 c2h0, s2h0, n2h0, c14h0, s14h0, n14h0;
        __half2 c2h1, s2h1, n2h1, c14h1, s14h1, n14h1;

        #pragma unroll 1
        for (int kk = 0; kk < 12; ++kk) {          // cos k-step; sin is kk+12
            // early-issue this step's 8 b-frags (latency hides under feature gen)
            short8 bfr[8];                          // [branch*4 + nt], static idx
            #pragma unroll
            for (int nt = 0; nt < 4; ++nt) {
                bfr[nt]     = Wlds[(kk*4 + nt)*64 + lane];
                bfr[4 + nt] = Wlds[((kk + 12)*4 + nt)*64 + lane];
            }

            if ((kk & 3) == 0) {                    // re-anchor per i-block (uniform)
                const int i = kk >> 2;
                const f32x2 a = xr[i];
                {   // row 0
                    const float av = a.x;
                    float u0 = hs*av;        u0 -= floorf(u0);
                    float u1 = (hs+1.f)*av;  u1 -= floorf(u1);
                    C0 = __floats2half2_rn(cos2pi(u0), cos2pi(u1));
                    S0 = __floats2half2_rn(sin2pi(u0), sin2pi(u1));
                    float t2 = 2.f*av;       t2 -= floorf(t2);
                    const float c2 = cos2pi(t2), s2 = sin2pi(t2);
                    float t14 = 14.f*av;     t14 -= floorf(t14);
                    const float c14 = cos2pi(t14), s14 = sin2pi(t14);
                    c2h0  = __float2half2_rn(c2);   s2h0  = __float2half2_rn(s2);
                    n2h0  = __float2half2_rn(-s2);
                    c14h0 = __float2half2_rn(c14);  s14h0 = __float2half2_rn(s14);
                    n14h0 = __float2half2_rn(-s14);
                }
                {   // row 1
                    const float av = a.y;
                    float u0 = hs*av;        u0 -= floorf(u0);
                    float u1 = (hs+1.f)*av;  u1 -= floorf(u1);
                    C1 = __floats2half2_rn(cos2pi(u0), cos2pi(u1));
                    S1 = __floats2half2_rn(sin2pi(u0), sin2pi(u1));
                    float t2 = 2.f*av;       t2 -= floorf(t2);
                    const float c2 = cos2pi(t2), s2 = sin2pi(t2);
                    float t14 = 14.f*av;     t14 -= floorf(t14);
                    const float c14 = cos2pi(t14), s14 = sin2pi(t14);
                    c2h1  = __float2half2_rn(c2);   s2h1  = __float2half2_rn(s2);
                    n2h1  = __float2half2_rn(-s2);
                    c14h1 = __float2half2_rn(c14);  s14h1 = __float2half2_rn(s14);
                    n14h1 = __float2half2_rn(-s14);
                }
            }

            // fragment dwords straight from chain state (no conversions)
            u32x4 FCA, FCB, FSA, FSB;
            FCA.x = h2b(C0); FSA.x = h2b(S0); FCB.x = h2b(C1); FSB.x = h2b(S1);
            ADV(C0, S0, c2h0,  s2h0,  n2h0);  ADV(C1, S1, c2h1,  s2h1,  n2h1);
            FCA.y = h2b(C0); FSA.y = h2b(S0); FCB.y = h2b(C1); FSB.y = h2b(S1);
            ADV(C0, S0, c14h0, s14h0, n14h0); ADV(C1, S1, c14h1, s14h1, n14h1);
            FCA.z = h2b(C0); FSA.z = h2b(S0); FCB.z = h2b(C1); FSB.z = h2b(S1);
            ADV(C0, S0, c2h0,  s2h0,  n2h0);  ADV(C1, S1, c2h1,  s2h1,  n2h1);
            FCA.w = h2b(C0); FSA.w = h2b(S0); FCB.w = h2b(C1); FSB.w = h2b(S1);
            ADV(C0, S0, c14h0, s14h0, n14h0); ADV(C1, S1, c14h1, s14h1, n14h1);
            // state now at harmonic anchor+32 = next kk's anchor

            const half8 fAc = u4h(FCA);
            const half8 fBc = u4h(FCB);
            const half8 fAs = u4h(FSA);
            const half8 fBs = u4h(FSB);

            #pragma unroll
            for (int nt = 0; nt < 4; ++nt) {
                acc[0][nt] = __builtin_amdgcn_mfma_f32_16x16x32_f16(fAc, s8h(bfr[nt]),   acc[0][nt], 0, 0, 0);
                acc[1][nt] = __builtin_amdgcn_mfma_f32_16x16x32_f16(fBc, s8h(bfr[nt]),   acc[1][nt], 0, 0, 0);
                acc[0][nt] = __builtin_amdgcn_mfma_f32_16x16x32_f16(fAs, s8h(bfr[4+nt]), acc[0][nt], 0, 0, 0);
                acc[1][nt] = __builtin_amdgcn_mfma_f32_16x16x32_f16(fBs, s8h(bfr[4+nt]), acc[1][nt], 0, 0, 0);
            }
        }

        // Epilogue. D layout: col = lane&15, row = 4*(lane>>4) + reg  [m89-verified]
        #pragma unroll
        for (int rr = 0; rr < 2; ++rr) {
            const int row0 = base + (rg*2 + rr)*16 + kgrp*4;
            #pragma unroll
            for (int nt = 0; nt < 4; ++nt) {
                #pragma unroll
                for (int q = 0; q < 4; ++q) {
                    out[(row0 + q)*ODIM + nt*16 + mrow] = acc[rr][nt][q] + bcol[nt];
                }
            }
        }
    }
}

extern "C" void kernel_launch(void* const* d_in, const int* in_sizes, int n_in,
                              void* d_out, int out_size, void* d_ws, size_t ws_size,
                              hipStream_t stream) {
    const float* x      = (const float*)d_in[0];
    const float* coeffs = (const float*)d_in[1];
    const float* bias   = (const float*)d_in[2];
    float* out = (float*)d_out;
    (void)in_sizes; (void)n_in; (void)out_size; (void)d_ws; (void)ws_size;
    hipLaunchKernelGGL(fourier_mfma, dim3(NBLOCKS), dim3(TPB), 0, stream, x, coeffs, bias, out);
}